// Round 5
// baseline (350.051 us; speedup 1.0000x reference)
//
#include <hip/hip_runtime.h>
#include <hip/hip_bf16.h>
#include <stdint.h>
#include <stddef.h>

// ---------- types ----------
typedef __bf16 b16;
typedef __bf16 b16x4 __attribute__((ext_vector_type(4)));
typedef __bf16 b16x8 __attribute__((ext_vector_type(8)));
typedef short  s16x4 __attribute__((ext_vector_type(4)));
typedef float  f32x4 __attribute__((ext_vector_type(4)));

#define LOG2E 1.4426950408889634f
#define QSCALE (0.125f * LOG2E)   // 1/sqrt(64) folded with log2(e): softmax in exp2 domain

#if __has_builtin(__builtin_amdgcn_exp2f)
#define EXP2F(x) __builtin_amdgcn_exp2f(x)
#else
#define EXP2F(x) exp2f(x)
#endif

typedef __attribute__((address_space(1))) void gvoid;
typedef __attribute__((address_space(3))) void svoid;

// async global->LDS, 16B per lane. LDS dest must be wave-uniform base + lane*16.
__device__ __forceinline__ void async_cp16(void* lds, const void* g) {
    __builtin_amdgcn_global_load_lds((gvoid*)(void*)g, (svoid*)lds, 16, 0, 0);
}

// ---------- kernel 1: x fp32 -> bf16 ----------
__global__ __launch_bounds__(256) void k_cvt_x(const float* __restrict__ x,
                                               b16* __restrict__ xb) {
    int i = (blockIdx.x * 256 + threadIdx.x) * 4;
    float4 v = *(const float4*)(x + i);
    b16x4 o = { (b16)v.x, (b16)v.y, (b16)v.z, (b16)v.w };
    *(b16x4*)(xb + i) = o;
}

// ---------- kernel 2: W[k][n] fp32 -> Wt[n][k] bf16 (per 32x32 tile) ----------
__global__ __launch_bounds__(256) void k_transpose(const float* __restrict__ Wq,
                                                   const float* __restrict__ Wk,
                                                   const float* __restrict__ Wv,
                                                   const float* __restrict__ Wo,
                                                   b16* __restrict__ WtQKV,
                                                   b16* __restrict__ Wot) {
    __shared__ float t[32][33];
    const int z = blockIdx.z;
    const float* W = (z == 0) ? Wq : (z == 1) ? Wk : (z == 2) ? Wv : Wo;
    const int k0 = blockIdx.x * 32, n0 = blockIdx.y * 32;
    const int tr = threadIdx.x >> 3, tc4 = (threadIdx.x & 7) * 4;
    float4 v = *(const float4*)(W + (size_t)(k0 + tr) * 1024 + n0 + tc4);
    t[tr][tc4 + 0] = v.x; t[tr][tc4 + 1] = v.y;
    t[tr][tc4 + 2] = v.z; t[tr][tc4 + 3] = v.w;
    __syncthreads();
    b16* dst = (z < 3) ? (WtQKV + ((size_t)z << 20)) : Wot;
    b16x4 o = { (b16)t[tc4 + 0][tr], (b16)t[tc4 + 1][tr],
                (b16)t[tc4 + 2][tr], (b16)t[tc4 + 3][tr] };
    *(b16x4*)(dst + (size_t)(n0 + tr) * 1024 + k0 + tc4) = o;
}

// ---------- GEMM 128x128 core, single-barrier double-buffered K-loop ----------
__device__ __forceinline__ void gemm_stage(const b16* __restrict__ Ab,
                                           const b16* __restrict__ Bb,
                                           b16* As, b16* Bs, int buf, int k0, int tid) {
    const int ci0 = tid, ci1 = tid + 256;
    b16* Ad = As + buf * 4096;
    b16* Bd = Bs + buf * 4096;
    async_cp16(Ad + ci0 * 8, Ab + (size_t)(ci0 >> 2) * 1024 + k0 + (ci0 & 3) * 8);
    async_cp16(Ad + ci1 * 8, Ab + (size_t)(ci1 >> 2) * 1024 + k0 + (ci1 & 3) * 8);
    async_cp16(Bd + ci0 * 8, Bb + (size_t)(ci0 >> 2) * 1024 + k0 + (ci0 & 3) * 8);
    async_cp16(Bd + ci1 * 8, Bb + (size_t)(ci1 >> 2) * 1024 + k0 + (ci1 & 3) * 8);
}

// One barrier per K-iter: stage issued AFTER barrier targets buf^1; the
// vmcnt(0) at the next barrier waits on loads a full compute window old.
__device__ __forceinline__ void gemm128_core(const b16* __restrict__ Ab,
                                             const b16* __restrict__ Bb,
                                             b16* As, b16* Bs, int tid,
                                             f32x4 acc[4][4]) {
    const int lane = tid & 63, wave = tid >> 6;
    const int wm = wave & 1, wn = wave >> 1;
    const int quad = lane >> 4, lc = lane & 15;
    gemm_stage(Ab, Bb, As, Bs, 0, 0, tid);
    int cur = 0;
    for (int k0 = 0; k0 < 1024; k0 += 32) {
        __syncthreads();
        if (k0 + 32 < 1024)
            gemm_stage(Ab, Bb, As, Bs, cur ^ 1, k0 + 32, tid);
        const b16* Ac = As + cur * 4096;
        const b16* Bc = Bs + cur * 4096;
        b16x8 af[4], bfr[4];
#pragma unroll
        for (int mt = 0; mt < 4; ++mt)
            af[mt] = *(const b16x8*)(Ac + (wm * 64 + mt * 16 + lc) * 32 + quad * 8);
#pragma unroll
        for (int nt = 0; nt < 4; ++nt)
            bfr[nt] = *(const b16x8*)(Bc + (wn * 64 + nt * 16 + lc) * 32 + quad * 8);
#pragma unroll
        for (int mt = 0; mt < 4; ++mt)
#pragma unroll
            for (int nt = 0; nt < 4; ++nt)
                acc[mt][nt] = __builtin_amdgcn_mfma_f32_16x16x32_bf16(
                    af[mt], bfr[nt], acc[mt][nt], 0, 0, 0);
        cur ^= 1;
    }
}

// ---------- kernel 3: fused QKV projection ----------
__global__ __launch_bounds__(256, 3) void k_gemm_qkv(
    const b16* __restrict__ A, const b16* __restrict__ Bt,
    const float* __restrict__ bq, const float* __restrict__ bk,
    const float* __restrict__ bv,
    b16* __restrict__ Qg, b16* __restrict__ Kg, b16* __restrict__ Vtg) {
    __shared__ __align__(16) b16 As[2 * 128 * 32];
    __shared__ __align__(16) b16 Bs[2 * 128 * 32];
    const int bm = blockIdx.x, bn = blockIdx.y;
    const int tid = threadIdx.x;
    const int lane = tid & 63, wave = tid >> 6;
    const int wm = wave & 1, wn = wave >> 1;
    const int quad = lane >> 4, lc = lane & 15;

    f32x4 acc[4][4] = {};
    gemm128_core(A + (size_t)(bm * 128) * 1024, Bt + (size_t)(bn * 128) * 1024,
                 As, Bs, tid, acc);

    const int mat = bn >> 3;
    const float* bp = (mat == 0) ? bq : (mat == 1) ? bk : bv;
#pragma unroll
    for (int nt = 0; nt < 4; ++nt) {
        const int n = bn * 128 + wn * 64 + nt * 16 + lc;
        const int cm = n & 1023;
        const int h = cm >> 6, dh = cm & 63;
        const float bval = bp[cm];
#pragma unroll
        for (int mt = 0; mt < 4; ++mt) {
            const int m0 = bm * 128 + wm * 64 + mt * 16 + quad * 4;
            const int b = m0 >> 11;
            const int bh = b * 16 + h;
            const int s0 = m0 & 2047;
            if (mat == 2) {
                b16x4 o;
#pragma unroll
                for (int r = 0; r < 4; ++r) o[r] = (b16)(acc[mt][nt][r] + bval);
                *(b16x4*)(Vtg + (size_t)(bh * 64 + dh) * 2048 + s0) = o;
            } else if (mat == 0) {
#pragma unroll
                for (int r = 0; r < 4; ++r)
                    Qg[(size_t)(bh * 2048 + s0 + r) * 64 + dh] =
                        (b16)((acc[mt][nt][r] + bval) * QSCALE);
            } else {
#pragma unroll
                for (int r = 0; r < 4; ++r)
                    Kg[(size_t)(bh * 2048 + s0 + r) * 64 + dh] =
                        (b16)(acc[mt][nt][r] + bval);
            }
        }
    }
}

// ---------- kernel 4: flash attention, np=1, 1 block/CU, structural L2 reuse ----------
// Grid (32 bh, 8 qb) = 256 blocks, all co-resident (1/CU). XCD = id%8 = bh%8:
// each XCD hosts 4 heads x 8 qb; K/V working set 2 MB < 4 MB L2, and the 8
// lockstep qb blocks hit L2 on 7/8 of K/V staging. No partials, no merge.
// P stays in registers: S^T via 16x16x32 (D: key=quad*4+r, q=lc) -> exp2 ->
// packed bf16x4 == B-operand of mfma_f32_16x16x16_bf16 -> O^T = V^T * P^T.
__global__ __launch_bounds__(256, 3) void k_flash(
    const b16* __restrict__ Qg, const b16* __restrict__ Kg,
    const b16* __restrict__ Vtg, b16* __restrict__ AO) {
    __shared__ __align__(16) b16 Ks[2][64 * 64];
    __shared__ __align__(16) b16 Vs[2][64 * 64];
    const int bh = blockIdx.x;        // 0..31 (x-fastest => bh%8 picks XCD)
    const int qb = blockIdx.y;        // 0..7 : 256-row q block
    const int tid = threadIdx.x, lane = tid & 63, wave = tid >> 6;
    const int quad = lane >> 4, lc = lane & 15;

    // Q fragments (B-operand of 16x16x32), 64 q rows per wave, resident all kernel
    const b16* Qbase = Qg + ((size_t)bh * 2048 + qb * 256 + wave * 64) * 64;
    b16x8 qf[4][2];
#pragma unroll
    for (int qt = 0; qt < 4; ++qt)
#pragma unroll
        for (int ch = 0; ch < 2; ++ch)
            qf[qt][ch] = *(const b16x8*)(Qbase + (qt * 16 + lc) * 64 + ch * 32 + quad * 8);

    // oacc[dt][qt] holds O^T: d = dt*16 + quad*4 + r, q = qt*16 + lc
    f32x4 oacc[4][4] = {};
    float lsum[4] = {0.f, 0.f, 0.f, 0.f};

    const b16* Kbh = Kg + (size_t)bh * 2048 * 64;
    const b16* Vbh = Vtg + (size_t)bh * 64 * 2048;

    const int ciA = tid, ciB = tid + 256;
    const int rA = ciA >> 3, gA = (ciA & 7) ^ (rA & 7);   // XOR chunk swizzle
    const int rB = ciB >> 3, gB = (ciB & 7) ^ (rB & 7);

    // prologue: stage tile 0 into buf 0
    async_cp16(&Ks[0][ciA * 8], Kbh + (size_t)(rA) * 64 + gA * 8);
    async_cp16(&Ks[0][ciB * 8], Kbh + (size_t)(rB) * 64 + gB * 8);
    async_cp16(&Vs[0][ciA * 8], Vbh + (size_t)rA * 2048 + gA * 8);
    async_cp16(&Vs[0][ciB * 8], Vbh + (size_t)rB * 2048 + gB * 8);
    int cur = 0;

    for (int kt = 0; kt < 32; ++kt) {
        __syncthreads();
        if (kt + 1 < 32) {
            const int nk = kt + 1, nb = cur ^ 1;
            async_cp16(&Ks[nb][ciA * 8], Kbh + (size_t)(nk * 64 + rA) * 64 + gA * 8);
            async_cp16(&Ks[nb][ciB * 8], Kbh + (size_t)(nk * 64 + rB) * 64 + gB * 8);
            async_cp16(&Vs[nb][ciA * 8], Vbh + (size_t)rA * 2048 + nk * 64 + gA * 8);
            async_cp16(&Vs[nb][ciB * 8], Vbh + (size_t)rB * 2048 + nk * 64 + gB * 8);
        }

        const b16* Kc = Ks[cur];
        const b16* Vc = Vs[cur];
#pragma unroll
        for (int m = 0; m < 4; ++m) {          // 16-key block
            const int row = m * 16 + lc;
            const b16x8 kf0 = *(const b16x8*)(Kc + row * 64 + ((quad) ^ (row & 7)) * 8);
            const b16x8 kf1 = *(const b16x8*)(Kc + row * 64 + ((4 + quad) ^ (row & 7)) * 8);

            s16x4 pb[4];
#pragma unroll
            for (int qt = 0; qt < 4; ++qt) {
                f32x4 s = {};
                s = __builtin_amdgcn_mfma_f32_16x16x32_bf16(kf0, qf[qt][0], s, 0, 0, 0);
                s = __builtin_amdgcn_mfma_f32_16x16x32_bf16(kf1, qf[qt][1], s, 0, 0, 0);
                const float e0 = EXP2F(s[0]), e1 = EXP2F(s[1]);
                const float e2 = EXP2F(s[2]), e3 = EXP2F(s[3]);
                lsum[qt] += (e0 + e1) + (e2 + e3);
                b16x4 p = { (b16)e0, (b16)e1, (b16)e2, (b16)e3 };
                pb[qt] = __builtin_bit_cast(s16x4, p);
            }
            // V^T fragments for key-step m: A[m=d][k=quad*4+j] -> b64 reads
            s16x4 vf[4];
#pragma unroll
            for (int dt = 0; dt < 4; ++dt) {
                const int vrow = dt * 16 + lc;
                const int chunk = (m * 2 + (quad >> 1)) ^ (vrow & 7);
                vf[dt] = *(const s16x4*)(Vc + vrow * 64 + chunk * 8 + (quad & 1) * 4);
            }
#pragma unroll
            for (int dt = 0; dt < 4; ++dt)
#pragma unroll
                for (int qt = 0; qt < 4; ++qt)
                    oacc[dt][qt] = __builtin_amdgcn_mfma_f32_16x16x16bf16_1k(
                        vf[dt], pb[qt], oacc[dt][qt], 0, 0, 0);
        }
        cur ^= 1;
    }

    // reduce l across quads (lane lc holds l for q = qt*16+lc after this)
#pragma unroll
    for (int qt = 0; qt < 4; ++qt) {
        lsum[qt] += __shfl_xor(lsum[qt], 16, 64);
        lsum[qt] += __shfl_xor(lsum[qt], 32, 64);
    }

    // direct epilogue: lane's q = lc matches lsum's q -> no redistribution
    const int b = bh >> 4, h = bh & 15;
#pragma unroll
    for (int qt = 0; qt < 4; ++qt) {
        const float inv = 1.0f / lsum[qt];
        const int s = qb * 256 + wave * 64 + qt * 16 + lc;
#pragma unroll
        for (int dt = 0; dt < 4; ++dt) {
            b16x4 ob = { (b16)(oacc[dt][qt][0] * inv), (b16)(oacc[dt][qt][1] * inv),
                         (b16)(oacc[dt][qt][2] * inv), (b16)(oacc[dt][qt][3] * inv) };
            *(b16x4*)(AO + (size_t)(b * 2048 + s) * 1024 + h * 64 + dt * 16 + quad * 4) = ob;
        }
    }
}

// ---------- kernel 5: output projection, 64x128 tiles, dbuf core ----------
__global__ __launch_bounds__(256, 2) void k_gemm_out(
    const b16* __restrict__ A, const b16* __restrict__ Bt,
    const float* __restrict__ bo, float* __restrict__ out) {
    __shared__ __align__(16) b16 As[2 * 64 * 32];
    __shared__ __align__(16) b16 Bs[2 * 128 * 32];
    const int bm = blockIdx.x, bn = blockIdx.y;
    const int tid = threadIdx.x;
    const int lane = tid & 63, wave = tid >> 6;
    const int wm = wave & 1, wn = wave >> 1;
    const int quad = lane >> 4, lc = lane & 15;
    const b16* Ab = A + (size_t)(bm * 64) * 1024;
    const b16* Bb = Bt + (size_t)(bn * 128) * 1024;

    const int ci0 = tid, ci1 = tid + 256;
    async_cp16(&As[ci0 * 8], Ab + (size_t)(ci0 >> 2) * 1024 + (ci0 & 3) * 8);
    async_cp16(&Bs[ci0 * 8], Bb + (size_t)(ci0 >> 2) * 1024 + (ci0 & 3) * 8);
    async_cp16(&Bs[ci1 * 8], Bb + (size_t)(ci1 >> 2) * 1024 + (ci1 & 3) * 8);

    f32x4 acc[2][4] = {};
    int cur = 0;
    for (int k0 = 0; k0 < 1024; k0 += 32) {
        __syncthreads();
        if (k0 + 32 < 1024) {
            const int kn = k0 + 32, nb = cur ^ 1;
            async_cp16(&As[nb * 2048 + ci0 * 8], Ab + (size_t)(ci0 >> 2) * 1024 + kn + (ci0 & 3) * 8);
            async_cp16(&Bs[nb * 4096 + ci0 * 8], Bb + (size_t)(ci0 >> 2) * 1024 + kn + (ci0 & 3) * 8);
            async_cp16(&Bs[nb * 4096 + ci1 * 8], Bb + (size_t)(ci1 >> 2) * 1024 + kn + (ci1 & 3) * 8);
        }
        const b16* Ac = &As[cur * 2048];
        const b16* Bc = &Bs[cur * 4096];
        b16x8 af[2], bfr[4];
#pragma unroll
        for (int mt = 0; mt < 2; ++mt)
            af[mt] = *(const b16x8*)(Ac + (wm * 32 + mt * 16 + lc) * 32 + quad * 8);
#pragma unroll
        for (int nt = 0; nt < 4; ++nt)
            bfr[nt] = *(const b16x8*)(Bc + (wn * 64 + nt * 16 + lc) * 32 + quad * 8);
#pragma unroll
        for (int mt = 0; mt < 2; ++mt)
#pragma unroll
            for (int nt = 0; nt < 4; ++nt)
                acc[mt][nt] = __builtin_amdgcn_mfma_f32_16x16x32_bf16(
                    af[mt], bfr[nt], acc[mt][nt], 0, 0, 0);
        cur ^= 1;
    }

#pragma unroll
    for (int nt = 0; nt < 4; ++nt) {
        const int n = bn * 128 + wn * 64 + nt * 16 + lc;
        const float bval = bo[n];
#pragma unroll
        for (int mt = 0; mt < 2; ++mt) {
            const int m0 = bm * 64 + wm * 32 + mt * 16 + quad * 4;
#pragma unroll
            for (int r = 0; r < 4; ++r)
                out[(size_t)(m0 + r) * 1024 + n] = acc[mt][nt][r] + bval;
        }
    }
}

// ---------- launcher ----------
extern "C" void kernel_launch(void* const* d_in, const int* in_sizes, int n_in,
                              void* d_out, int out_size, void* d_ws, size_t ws_size,
                              hipStream_t stream) {
    const float* x  = (const float*)d_in[0];
    const float* Wq = (const float*)d_in[1];
    const float* bq = (const float*)d_in[2];
    const float* Wk = (const float*)d_in[3];
    const float* bk = (const float*)d_in[4];
    const float* Wv = (const float*)d_in[5];
    const float* bv = (const float*)d_in[6];
    const float* Wo = (const float*)d_in[7];
    const float* bo = (const float*)d_in[8];
    float* out = (float*)d_out;

    char* ws = (char*)d_ws;
    const size_t MB = 1024 * 1024;
    b16* Xb  = (b16*)(ws);             // [4096][1024] bf16 (dead after qkv)
    b16* AO  = (b16*)(ws);             // [4096][1024] bf16 (overlay on Xb)
    b16* WtQ = (b16*)(ws + 8 * MB);    // [3072][1024] bf16
    b16* Wot = (b16*)(ws + 14 * MB);   // [1024][1024] bf16
    b16* Qg  = (b16*)(ws + 16 * MB);   // [32][2048][64] bf16 (pre-scaled)
    b16* Kg  = (b16*)(ws + 24 * MB);   // [32][2048][64] bf16
    b16* Vtg = (b16*)(ws + 32 * MB);   // [32][64][2048] bf16

    k_cvt_x<<<4096, 256, 0, stream>>>(x, Xb);
    k_transpose<<<dim3(32, 32, 4), 256, 0, stream>>>(Wq, Wk, Wv, Wo, WtQ, Wot);
    k_gemm_qkv<<<dim3(32, 24), 256, 0, stream>>>(Xb, WtQ, bq, bk, bv, Qg, Kg, Vtg);
    k_flash<<<dim3(32, 8), 256, 0, stream>>>(Qg, Kg, Vtg, AO);
    k_gemm_out<<<dim3(64, 8), 256, 0, stream>>>(AO, Wot, bo, out);
}

// Round 6
// 208.677 us; speedup vs baseline: 1.6775x; 1.6775x over previous
//
#include <hip/hip_runtime.h>
#include <hip/hip_bf16.h>
#include <stdint.h>
#include <stddef.h>

// ---------- types ----------
typedef __bf16 b16;
typedef __bf16 b16x4 __attribute__((ext_vector_type(4)));
typedef __bf16 b16x8 __attribute__((ext_vector_type(8)));
typedef short  s16x4 __attribute__((ext_vector_type(4)));
typedef float  f32x4 __attribute__((ext_vector_type(4)));

#define LOG2E 1.4426950408889634f
#define QSCALE (0.125f * LOG2E)   // 1/sqrt(64) folded with log2(e): softmax in exp2 domain

#if __has_builtin(__builtin_amdgcn_exp2f)
#define EXP2F(x) __builtin_amdgcn_exp2f(x)
#else
#define EXP2F(x) exp2f(x)
#endif

typedef __attribute__((address_space(1))) void gvoid;
typedef __attribute__((address_space(3))) void svoid;

// async global->LDS, 16B per lane. LDS dest must be wave-uniform base + lane*16.
__device__ __forceinline__ void async_cp16(void* lds, const void* g) {
    __builtin_amdgcn_global_load_lds((gvoid*)(void*)g, (svoid*)lds, 16, 0, 0);
}

// ---------- kernel 1: x fp32 -> bf16 ----------
__global__ __launch_bounds__(256) void k_cvt_x(const float* __restrict__ x,
                                               b16* __restrict__ xb) {
    int i = (blockIdx.x * 256 + threadIdx.x) * 4;
    float4 v = *(const float4*)(x + i);
    b16x4 o = { (b16)v.x, (b16)v.y, (b16)v.z, (b16)v.w };
    *(b16x4*)(xb + i) = o;
}

// ---------- kernel 2: W[k][n] fp32 -> Wt[n][k] bf16 (per 32x32 tile) ----------
__global__ __launch_bounds__(256) void k_transpose(const float* __restrict__ Wq,
                                                   const float* __restrict__ Wk,
                                                   const float* __restrict__ Wv,
                                                   const float* __restrict__ Wo,
                                                   b16* __restrict__ WtQKV,
                                                   b16* __restrict__ Wot) {
    __shared__ float t[32][33];
    const int z = blockIdx.z;
    const float* W = (z == 0) ? Wq : (z == 1) ? Wk : (z == 2) ? Wv : Wo;
    const int k0 = blockIdx.x * 32, n0 = blockIdx.y * 32;
    const int tr = threadIdx.x >> 3, tc4 = (threadIdx.x & 7) * 4;
    float4 v = *(const float4*)(W + (size_t)(k0 + tr) * 1024 + n0 + tc4);
    t[tr][tc4 + 0] = v.x; t[tr][tc4 + 1] = v.y;
    t[tr][tc4 + 2] = v.z; t[tr][tc4 + 3] = v.w;
    __syncthreads();
    b16* dst = (z < 3) ? (WtQKV + ((size_t)z << 20)) : Wot;
    b16x4 o = { (b16)t[tc4 + 0][tr], (b16)t[tc4 + 1][tr],
                (b16)t[tc4 + 2][tr], (b16)t[tc4 + 3][tr] };
    *(b16x4*)(dst + (size_t)(n0 + tr) * 1024 + k0 + tc4) = o;
}

// ---------- GEMM 128x128 core, single-barrier double-buffered K-loop ----------
__device__ __forceinline__ void gemm_stage(const b16* __restrict__ Ab,
                                           const b16* __restrict__ Bb,
                                           b16* As, b16* Bs, int buf, int k0, int tid) {
    const int ci0 = tid, ci1 = tid + 256;
    b16* Ad = As + buf * 4096;
    b16* Bd = Bs + buf * 4096;
    async_cp16(Ad + ci0 * 8, Ab + (size_t)(ci0 >> 2) * 1024 + k0 + (ci0 & 3) * 8);
    async_cp16(Ad + ci1 * 8, Ab + (size_t)(ci1 >> 2) * 1024 + k0 + (ci1 & 3) * 8);
    async_cp16(Bd + ci0 * 8, Bb + (size_t)(ci0 >> 2) * 1024 + k0 + (ci0 & 3) * 8);
    async_cp16(Bd + ci1 * 8, Bb + (size_t)(ci1 >> 2) * 1024 + k0 + (ci1 & 3) * 8);
}

// One barrier per K-iter: stage issued AFTER barrier targets buf^1; the
// vmcnt(0) at the next barrier waits on loads a full compute window old.
__device__ __forceinline__ void gemm128_core(const b16* __restrict__ Ab,
                                             const b16* __restrict__ Bb,
                                             b16* As, b16* Bs, int tid,
                                             f32x4 acc[4][4]) {
    const int lane = tid & 63, wave = tid >> 6;
    const int wm = wave & 1, wn = wave >> 1;
    const int quad = lane >> 4, lc = lane & 15;
    gemm_stage(Ab, Bb, As, Bs, 0, 0, tid);
    int cur = 0;
    for (int k0 = 0; k0 < 1024; k0 += 32) {
        __syncthreads();
        if (k0 + 32 < 1024)
            gemm_stage(Ab, Bb, As, Bs, cur ^ 1, k0 + 32, tid);
        const b16* Ac = As + cur * 4096;
        const b16* Bc = Bs + cur * 4096;
        b16x8 af[4], bfr[4];
#pragma unroll
        for (int mt = 0; mt < 4; ++mt)
            af[mt] = *(const b16x8*)(Ac + (wm * 64 + mt * 16 + lc) * 32 + quad * 8);
#pragma unroll
        for (int nt = 0; nt < 4; ++nt)
            bfr[nt] = *(const b16x8*)(Bc + (wn * 64 + nt * 16 + lc) * 32 + quad * 8);
#pragma unroll
        for (int mt = 0; mt < 4; ++mt)
#pragma unroll
            for (int nt = 0; nt < 4; ++nt)
                acc[mt][nt] = __builtin_amdgcn_mfma_f32_16x16x32_bf16(
                    af[mt], bfr[nt], acc[mt][nt], 0, 0, 0);
        cur ^= 1;
    }
}

// ---------- kernel 3: fused QKV projection ----------
// Epilogue rules learned r2-r5: every global store must be lane-contiguous.
// Q/K: 16-lane x 2B = 32B segments that merge in L2 (direct store ok).
// V^T: natural pattern is 8B/lane at 4KB lane-stride (40x write amplification)
//      -> bounce through the dead LDS staging buffers, write 256B contiguous.
__global__ __launch_bounds__(256, 3) void k_gemm_qkv(
    const b16* __restrict__ A, const b16* __restrict__ Bt,
    const float* __restrict__ bq, const float* __restrict__ bk,
    const float* __restrict__ bv,
    b16* __restrict__ Qg, b16* __restrict__ Kg, b16* __restrict__ Vtg) {
    __shared__ __align__(16) b16 SM[2 * 128 * 32 * 2];   // As dbuf | Bs dbuf (32 KB)
    b16* As = SM;
    b16* Bs = SM + 8192;
    const int bm = blockIdx.x, bn = blockIdx.y;
    const int tid = threadIdx.x;
    const int lane = tid & 63, wave = tid >> 6;
    const int wm = wave & 1, wn = wave >> 1;
    const int quad = lane >> 4, lc = lane & 15;

    f32x4 acc[4][4] = {};
    gemm128_core(A + (size_t)(bm * 128) * 1024, Bt + (size_t)(bn * 128) * 1024,
                 As, Bs, tid, acc);

    const int mat = bn >> 3;   // uniform per block
    if (mat == 2) {
        // V^T via LDS bounce: Sl[64 n][136 m] bf16 (17 KB, aliases staging)
        b16* Sl = SM;
        const int b = (bm * 128) >> 11;
        const int s0 = (bm * 128) & 2047;
        const int bh2base = b * 16 + (bn - 16) * 2;
#pragma unroll
        for (int rd = 0; rd < 2; ++rd) {
            __syncthreads();   // rd0: waves done reading staging; rd1: reads done
            if (wn == rd) {
#pragma unroll
                for (int nt = 0; nt < 4; ++nt) {
                    const int cm = (bn * 128 + wn * 64 + nt * 16 + lc) & 1023;
                    const float bval = bv[cm];
#pragma unroll
                    for (int mt = 0; mt < 4; ++mt) {
                        b16x4 o = { (b16)(acc[mt][nt][0] + bval),
                                    (b16)(acc[mt][nt][1] + bval),
                                    (b16)(acc[mt][nt][2] + bval),
                                    (b16)(acc[mt][nt][3] + bval) };
                        *(b16x4*)(Sl + (nt * 16 + lc) * 136 + wm * 64 + mt * 16 + quad * 4) = o;
                    }
                }
            }
            __syncthreads();
            const int bh2 = bh2base + rd;
#pragma unroll
            for (int p = 0; p < 4; ++p) {
                const int n = p * 16 + (tid >> 4), c = tid & 15;
                b16x8 v = *(const b16x8*)(Sl + n * 136 + c * 8);
                *(b16x8*)(Vtg + (size_t)(bh2 * 64 + n) * 2048 + s0 + c * 8) = v;
            }
        }
        return;
    }

    const float* bp = (mat == 0) ? bq : bk;
#pragma unroll
    for (int nt = 0; nt < 4; ++nt) {
        const int n = bn * 128 + wn * 64 + nt * 16 + lc;
        const int cm = n & 1023;
        const int h = cm >> 6, dh = cm & 63;
        const float bval = bp[cm];
#pragma unroll
        for (int mt = 0; mt < 4; ++mt) {
            const int m0 = bm * 128 + wm * 64 + mt * 16 + quad * 4;
            const int b = m0 >> 11;
            const int bh = b * 16 + h;
            const int s0 = m0 & 2047;
            if (mat == 0) {
#pragma unroll
                for (int r = 0; r < 4; ++r)
                    Qg[(size_t)(bh * 2048 + s0 + r) * 64 + dh] =
                        (b16)((acc[mt][nt][r] + bval) * QSCALE);
            } else {
#pragma unroll
                for (int r = 0; r < 4; ++r)
                    Kg[(size_t)(bh * 2048 + s0 + r) * 64 + dh] =
                        (b16)(acc[mt][nt][r] + bval);
            }
        }
    }
}

// ---------- kernel 4: flash attention ----------
// Grid (32 bh, 8 qb) = 256 blocks, 1/CU, all co-resident; XCD = bh%8 so each
// XCD hosts 4 heads and the 8 lockstep qb blocks hit L2 on K/V (r5: FETCH
// 23.5 MB, confirmed). P stays in registers (S^T 16x16x32 -> exp2 -> packed
// bf16x4 == B-operand of 16x16x16 -> O^T = V^T * P^T). Epilogue bounces O
// through LDS so AO writes are 128B lane-contiguous (r5's 331 MB fix).
__global__ __launch_bounds__(256) void k_flash(
    const b16* __restrict__ Qg, const b16* __restrict__ Kg,
    const b16* __restrict__ Vtg, b16* __restrict__ AO) {
    __shared__ __align__(16) b16 Ks[2][64 * 64];
    __shared__ __align__(16) b16 Vs[2][64 * 64];
    __shared__ __align__(16) b16 Es[256 * 72];   // epilogue bounce (36 KB)
    const int bh = blockIdx.x;        // 0..31 (x-fastest => bh%8 picks XCD)
    const int qb = blockIdx.y;        // 0..7 : 256-row q block
    const int tid = threadIdx.x, lane = tid & 63, wave = tid >> 6;
    const int quad = lane >> 4, lc = lane & 15;

    // Q fragments (B-operand of 16x16x32), 64 q rows per wave, resident all kernel
    const b16* Qbase = Qg + ((size_t)bh * 2048 + qb * 256 + wave * 64) * 64;
    b16x8 qf[4][2];
#pragma unroll
    for (int qt = 0; qt < 4; ++qt)
#pragma unroll
        for (int ch = 0; ch < 2; ++ch)
            qf[qt][ch] = *(const b16x8*)(Qbase + (qt * 16 + lc) * 64 + ch * 32 + quad * 8);

    // oacc[dt][qt] holds O^T: d = dt*16 + quad*4 + r, q = qt*16 + lc
    f32x4 oacc[4][4] = {};
    float lsum[4] = {0.f, 0.f, 0.f, 0.f};

    const b16* Kbh = Kg + (size_t)bh * 2048 * 64;
    const b16* Vbh = Vtg + (size_t)bh * 64 * 2048;

    const int ciA = tid, ciB = tid + 256;
    const int rA = ciA >> 3, gA = (ciA & 7) ^ (rA & 7);   // XOR chunk swizzle
    const int rB = ciB >> 3, gB = (ciB & 7) ^ (rB & 7);

    // prologue: stage tile 0 into buf 0
    async_cp16(&Ks[0][ciA * 8], Kbh + (size_t)(rA) * 64 + gA * 8);
    async_cp16(&Ks[0][ciB * 8], Kbh + (size_t)(rB) * 64 + gB * 8);
    async_cp16(&Vs[0][ciA * 8], Vbh + (size_t)rA * 2048 + gA * 8);
    async_cp16(&Vs[0][ciB * 8], Vbh + (size_t)rB * 2048 + gB * 8);
    int cur = 0;

    for (int kt = 0; kt < 32; ++kt) {
        __syncthreads();
        if (kt + 1 < 32) {
            const int nk = kt + 1, nb = cur ^ 1;
            async_cp16(&Ks[nb][ciA * 8], Kbh + (size_t)(nk * 64 + rA) * 64 + gA * 8);
            async_cp16(&Ks[nb][ciB * 8], Kbh + (size_t)(nk * 64 + rB) * 64 + gB * 8);
            async_cp16(&Vs[nb][ciA * 8], Vbh + (size_t)rA * 2048 + nk * 64 + gA * 8);
            async_cp16(&Vs[nb][ciB * 8], Vbh + (size_t)rB * 2048 + nk * 64 + gB * 8);
        }

        const b16* Kc = Ks[cur];
        const b16* Vc = Vs[cur];
#pragma unroll
        for (int m = 0; m < 4; ++m) {          // 16-key block
            const int row = m * 16 + lc;
            const b16x8 kf0 = *(const b16x8*)(Kc + row * 64 + ((quad) ^ (row & 7)) * 8);
            const b16x8 kf1 = *(const b16x8*)(Kc + row * 64 + ((4 + quad) ^ (row & 7)) * 8);

            s16x4 pb[4];
#pragma unroll
            for (int qt = 0; qt < 4; ++qt) {
                f32x4 s = {};
                s = __builtin_amdgcn_mfma_f32_16x16x32_bf16(kf0, qf[qt][0], s, 0, 0, 0);
                s = __builtin_amdgcn_mfma_f32_16x16x32_bf16(kf1, qf[qt][1], s, 0, 0, 0);
                const float e0 = EXP2F(s[0]), e1 = EXP2F(s[1]);
                const float e2 = EXP2F(s[2]), e3 = EXP2F(s[3]);
                lsum[qt] += (e0 + e1) + (e2 + e3);
                b16x4 p = { (b16)e0, (b16)e1, (b16)e2, (b16)e3 };
                pb[qt] = __builtin_bit_cast(s16x4, p);
            }
            // V^T fragments for key-step m: A[m=d][k=quad*4+j] -> b64 reads
            s16x4 vf[4];
#pragma unroll
            for (int dt = 0; dt < 4; ++dt) {
                const int vrow = dt * 16 + lc;
                const int chunk = (m * 2 + (quad >> 1)) ^ (vrow & 7);
                vf[dt] = *(const s16x4*)(Vc + vrow * 64 + chunk * 8 + (quad & 1) * 4);
            }
#pragma unroll
            for (int dt = 0; dt < 4; ++dt)
#pragma unroll
                for (int qt = 0; qt < 4; ++qt)
                    oacc[dt][qt] = __builtin_amdgcn_mfma_f32_16x16x16bf16_1k(
                        vf[dt], pb[qt], oacc[dt][qt], 0, 0, 0);
        }
        cur ^= 1;
    }

    // reduce l across quads (lane lc holds l for q = qt*16+lc after this)
#pragma unroll
    for (int qt = 0; qt < 4; ++qt) {
        lsum[qt] += __shfl_xor(lsum[qt], 16, 64);
        lsum[qt] += __shfl_xor(lsum[qt], 32, 64);
    }

    // epilogue via LDS bounce: wave-private Es rows -> no barrier before store
    const int b = bh >> 4, h = bh & 15;
#pragma unroll
    for (int qt = 0; qt < 4; ++qt) {
        const float inv = 1.0f / lsum[qt];
        const int qrow = wave * 64 + qt * 16 + lc;
#pragma unroll
        for (int dt = 0; dt < 4; ++dt) {
            b16x4 ob = { (b16)(oacc[dt][qt][0] * inv), (b16)(oacc[dt][qt][1] * inv),
                         (b16)(oacc[dt][qt][2] * inv), (b16)(oacc[dt][qt][3] * inv) };
            *(b16x4*)(Es + qrow * 72 + dt * 16 + quad * 4) = ob;
        }
    }
    __syncthreads();
    const size_t aobase = (size_t)(b * 2048 + qb * 256) * 1024 + h * 64;
#pragma unroll
    for (int p = 0; p < 8; ++p) {
        const int q = p * 32 + (tid >> 3);
        const int c = tid & 7;
        b16x8 v = *(const b16x8*)(Es + q * 72 + c * 8);
        *(b16x8*)(AO + aobase + (size_t)q * 1024 + c * 8) = v;   // 128B/row contiguous
    }
}

// ---------- kernel 5: output projection, 64x128 tiles, dbuf core ----------
__global__ __launch_bounds__(256, 2) void k_gemm_out(
    const b16* __restrict__ A, const b16* __restrict__ Bt,
    const float* __restrict__ bo, float* __restrict__ out) {
    __shared__ __align__(16) b16 As[2 * 64 * 32];
    __shared__ __align__(16) b16 Bs[2 * 128 * 32];
    const int bm = blockIdx.x, bn = blockIdx.y;
    const int tid = threadIdx.x;
    const int lane = tid & 63, wave = tid >> 6;
    const int wm = wave & 1, wn = wave >> 1;
    const int quad = lane >> 4, lc = lane & 15;
    const b16* Ab = A + (size_t)(bm * 64) * 1024;
    const b16* Bb = Bt + (size_t)(bn * 128) * 1024;

    const int ci0 = tid, ci1 = tid + 256;
    async_cp16(&As[ci0 * 8], Ab + (size_t)(ci0 >> 2) * 1024 + (ci0 & 3) * 8);
    async_cp16(&Bs[ci0 * 8], Bb + (size_t)(ci0 >> 2) * 1024 + (ci0 & 3) * 8);
    async_cp16(&Bs[ci1 * 8], Bb + (size_t)(ci1 >> 2) * 1024 + (ci1 & 3) * 8);

    f32x4 acc[2][4] = {};
    int cur = 0;
    for (int k0 = 0; k0 < 1024; k0 += 32) {
        __syncthreads();
        if (k0 + 32 < 1024) {
            const int kn = k0 + 32, nb = cur ^ 1;
            async_cp16(&As[nb * 2048 + ci0 * 8], Ab + (size_t)(ci0 >> 2) * 1024 + kn + (ci0 & 3) * 8);
            async_cp16(&Bs[nb * 4096 + ci0 * 8], Bb + (size_t)(ci0 >> 2) * 1024 + kn + (ci0 & 3) * 8);
            async_cp16(&Bs[nb * 4096 + ci1 * 8], Bb + (size_t)(ci1 >> 2) * 1024 + kn + (ci1 & 3) * 8);
        }
        const b16* Ac = &As[cur * 2048];
        const b16* Bc = &Bs[cur * 4096];
        b16x8 af[2], bfr[4];
#pragma unroll
        for (int mt = 0; mt < 2; ++mt)
            af[mt] = *(const b16x8*)(Ac + (wm * 32 + mt * 16 + lc) * 32 + quad * 8);
#pragma unroll
        for (int nt = 0; nt < 4; ++nt)
            bfr[nt] = *(const b16x8*)(Bc + (wn * 64 + nt * 16 + lc) * 32 + quad * 8);
#pragma unroll
        for (int mt = 0; mt < 2; ++mt)
#pragma unroll
            for (int nt = 0; nt < 4; ++nt)
                acc[mt][nt] = __builtin_amdgcn_mfma_f32_16x16x32_bf16(
                    af[mt], bfr[nt], acc[mt][nt], 0, 0, 0);
        cur ^= 1;
    }

#pragma unroll
    for (int nt = 0; nt < 4; ++nt) {
        const int n = bn * 128 + wn * 64 + nt * 16 + lc;
        const float bval = bo[n];
#pragma unroll
        for (int mt = 0; mt < 2; ++mt) {
            const int m0 = bm * 64 + wm * 32 + mt * 16 + quad * 4;
#pragma unroll
            for (int r = 0; r < 4; ++r)
                out[(size_t)(m0 + r) * 1024 + n] = acc[mt][nt][r] + bval;  // 64B/quad contiguous
        }
    }
}

// ---------- launcher ----------
extern "C" void kernel_launch(void* const* d_in, const int* in_sizes, int n_in,
                              void* d_out, int out_size, void* d_ws, size_t ws_size,
                              hipStream_t stream) {
    const float* x  = (const float*)d_in[0];
    const float* Wq = (const float*)d_in[1];
    const float* bq = (const float*)d_in[2];
    const float* Wk = (const float*)d_in[3];
    const float* bk = (const float*)d_in[4];
    const float* Wv = (const float*)d_in[5];
    const float* bv = (const float*)d_in[6];
    const float* Wo = (const float*)d_in[7];
    const float* bo = (const float*)d_in[8];
    float* out = (float*)d_out;

    char* ws = (char*)d_ws;
    const size_t MB = 1024 * 1024;
    b16* Xb  = (b16*)(ws);             // [4096][1024] bf16 (dead after qkv)
    b16* AO  = (b16*)(ws);             // [4096][1024] bf16 (overlay on Xb)
    b16* WtQ = (b16*)(ws + 8 * MB);    // [3072][1024] bf16
    b16* Wot = (b16*)(ws + 14 * MB);   // [1024][1024] bf16
    b16* Qg  = (b16*)(ws + 16 * MB);   // [32][2048][64] bf16 (pre-scaled)
    b16* Kg  = (b16*)(ws + 24 * MB);   // [32][2048][64] bf16
    b16* Vtg = (b16*)(ws + 32 * MB);   // [32][64][2048] bf16

    k_cvt_x<<<4096, 256, 0, stream>>>(x, Xb);
    k_transpose<<<dim3(32, 32, 4), 256, 0, stream>>>(Wq, Wk, Wv, Wo, WtQ, Wot);
    k_gemm_qkv<<<dim3(32, 24), 256, 0, stream>>>(Xb, WtQ, bq, bk, bv, Qg, Kg, Vtg);
    k_flash<<<dim3(32, 8), 256, 0, stream>>>(Qg, Kg, Vtg, AO);
    k_gemm_out<<<dim3(64, 8), 256, 0, stream>>>(AO, Wot, bo, out);
}

// Round 7
// 204.747 us; speedup vs baseline: 1.7097x; 1.0192x over previous
//
#include <hip/hip_runtime.h>
#include <hip/hip_bf16.h>
#include <stdint.h>
#include <stddef.h>

// ---------- types ----------
typedef __bf16 b16;
typedef __bf16 b16x4 __attribute__((ext_vector_type(4)));
typedef __bf16 b16x8 __attribute__((ext_vector_type(8)));
typedef short  s16x4 __attribute__((ext_vector_type(4)));
typedef float  f32x4 __attribute__((ext_vector_type(4)));

#define LOG2E 1.4426950408889634f
#define QSCALE (0.125f * LOG2E)   // 1/sqrt(64) folded with log2(e): softmax in exp2 domain

#if __has_builtin(__builtin_amdgcn_exp2f)
#define EXP2F(x) __builtin_amdgcn_exp2f(x)
#else
#define EXP2F(x) exp2f(x)
#endif

typedef __attribute__((address_space(1))) void gvoid;
typedef __attribute__((address_space(3))) void svoid;

// async global->LDS, 16B per lane. LDS dest must be wave-uniform base + lane*16.
__device__ __forceinline__ void async_cp16(void* lds, const void* g) {
    __builtin_amdgcn_global_load_lds((gvoid*)(void*)g, (svoid*)lds, 16, 0, 0);
}

// ---------- kernel 1: x fp32 -> bf16 ----------
__global__ __launch_bounds__(256) void k_cvt_x(const float* __restrict__ x,
                                               b16* __restrict__ xb) {
    int i = (blockIdx.x * 256 + threadIdx.x) * 4;
    float4 v = *(const float4*)(x + i);
    b16x4 o = { (b16)v.x, (b16)v.y, (b16)v.z, (b16)v.w };
    *(b16x4*)(xb + i) = o;
}

// ---------- kernel 2: W[k][n] fp32 -> Wt[n][k] bf16 (per 32x32 tile) ----------
__global__ __launch_bounds__(256) void k_transpose(const float* __restrict__ Wq,
                                                   const float* __restrict__ Wk,
                                                   const float* __restrict__ Wv,
                                                   const float* __restrict__ Wo,
                                                   b16* __restrict__ WtQKV,
                                                   b16* __restrict__ Wot) {
    __shared__ float t[32][33];
    const int z = blockIdx.z;
    const float* W = (z == 0) ? Wq : (z == 1) ? Wk : (z == 2) ? Wv : Wo;
    const int k0 = blockIdx.x * 32, n0 = blockIdx.y * 32;
    const int tr = threadIdx.x >> 3, tc4 = (threadIdx.x & 7) * 4;
    float4 v = *(const float4*)(W + (size_t)(k0 + tr) * 1024 + n0 + tc4);
    t[tr][tc4 + 0] = v.x; t[tr][tc4 + 1] = v.y;
    t[tr][tc4 + 2] = v.z; t[tr][tc4 + 3] = v.w;
    __syncthreads();
    b16* dst = (z < 3) ? (WtQKV + ((size_t)z << 20)) : Wot;
    b16x4 o = { (b16)t[tc4 + 0][tr], (b16)t[tc4 + 1][tr],
                (b16)t[tc4 + 2][tr], (b16)t[tc4 + 3][tr] };
    *(b16x4*)(dst + (size_t)(n0 + tr) * 1024 + k0 + tc4) = o;
}

// ---------- GEMM 128x128 core, single-barrier double-buffered K-loop ----------
__device__ __forceinline__ void gemm_stage(const b16* __restrict__ Ab,
                                           const b16* __restrict__ Bb,
                                           b16* As, b16* Bs, int buf, int k0, int tid) {
    const int ci0 = tid, ci1 = tid + 256;
    b16* Ad = As + buf * 4096;
    b16* Bd = Bs + buf * 4096;
    async_cp16(Ad + ci0 * 8, Ab + (size_t)(ci0 >> 2) * 1024 + k0 + (ci0 & 3) * 8);
    async_cp16(Ad + ci1 * 8, Ab + (size_t)(ci1 >> 2) * 1024 + k0 + (ci1 & 3) * 8);
    async_cp16(Bd + ci0 * 8, Bb + (size_t)(ci0 >> 2) * 1024 + k0 + (ci0 & 3) * 8);
    async_cp16(Bd + ci1 * 8, Bb + (size_t)(ci1 >> 2) * 1024 + k0 + (ci1 & 3) * 8);
}

// One barrier per K-iter: stage issued AFTER barrier targets buf^1; the
// vmcnt(0) at the next barrier waits on loads a full compute window old.
__device__ __forceinline__ void gemm128_core(const b16* __restrict__ Ab,
                                             const b16* __restrict__ Bb,
                                             b16* As, b16* Bs, int tid,
                                             f32x4 acc[4][4]) {
    const int lane = tid & 63, wave = tid >> 6;
    const int wm = wave & 1, wn = wave >> 1;
    const int quad = lane >> 4, lc = lane & 15;
    gemm_stage(Ab, Bb, As, Bs, 0, 0, tid);
    int cur = 0;
    for (int k0 = 0; k0 < 1024; k0 += 32) {
        __syncthreads();
        if (k0 + 32 < 1024)
            gemm_stage(Ab, Bb, As, Bs, cur ^ 1, k0 + 32, tid);
        const b16* Ac = As + cur * 4096;
        const b16* Bc = Bs + cur * 4096;
        b16x8 af[4], bfr[4];
#pragma unroll
        for (int mt = 0; mt < 4; ++mt)
            af[mt] = *(const b16x8*)(Ac + (wm * 64 + mt * 16 + lc) * 32 + quad * 8);
#pragma unroll
        for (int nt = 0; nt < 4; ++nt)
            bfr[nt] = *(const b16x8*)(Bc + (wn * 64 + nt * 16 + lc) * 32 + quad * 8);
#pragma unroll
        for (int mt = 0; mt < 4; ++mt)
#pragma unroll
            for (int nt = 0; nt < 4; ++nt)
                acc[mt][nt] = __builtin_amdgcn_mfma_f32_16x16x32_bf16(
                    af[mt], bfr[nt], acc[mt][nt], 0, 0, 0);
        cur ^= 1;
    }
}

// ---------- kernel 3: fused QKV projection ----------
// Grid: bn on x so each XCD's resident blocks share B-tiles (L2-resident).
// Store rules (r2-r6): global stores must be lane-contiguous. Q/K: 32B
// segments, ok. V^T: bounce via dead LDS staging, 256B-contiguous stores.
__global__ __launch_bounds__(256, 3) void k_gemm_qkv(
    const b16* __restrict__ A, const b16* __restrict__ Bt,
    const float* __restrict__ bq, const float* __restrict__ bk,
    const float* __restrict__ bv,
    b16* __restrict__ Qg, b16* __restrict__ Kg, b16* __restrict__ Vtg) {
    __shared__ __align__(16) b16 SM[2 * 128 * 32 * 2];   // As dbuf | Bs dbuf (32 KB)
    b16* As = SM;
    b16* Bs = SM + 8192;
    const int bn = blockIdx.x, bm = blockIdx.y;
    const int tid = threadIdx.x;
    const int lane = tid & 63, wave = tid >> 6;
    const int wm = wave & 1, wn = wave >> 1;
    const int quad = lane >> 4, lc = lane & 15;

    f32x4 acc[4][4] = {};
    gemm128_core(A + (size_t)(bm * 128) * 1024, Bt + (size_t)(bn * 128) * 1024,
                 As, Bs, tid, acc);

    const int mat = bn >> 3;   // uniform per block
    if (mat == 2) {
        // V^T via LDS bounce: Sl[64 n][136 m] bf16 (17 KB, aliases staging)
        b16* Sl = SM;
        const int b = (bm * 128) >> 11;
        const int s0 = (bm * 128) & 2047;
        const int bh2base = b * 16 + (bn - 16) * 2;
#pragma unroll
        for (int rd = 0; rd < 2; ++rd) {
            __syncthreads();   // rd0: waves done reading staging; rd1: reads done
            if (wn == rd) {
#pragma unroll
                for (int nt = 0; nt < 4; ++nt) {
                    const int cm = (bn * 128 + wn * 64 + nt * 16 + lc) & 1023;
                    const float bval = bv[cm];
#pragma unroll
                    for (int mt = 0; mt < 4; ++mt) {
                        b16x4 o = { (b16)(acc[mt][nt][0] + bval),
                                    (b16)(acc[mt][nt][1] + bval),
                                    (b16)(acc[mt][nt][2] + bval),
                                    (b16)(acc[mt][nt][3] + bval) };
                        *(b16x4*)(Sl + (nt * 16 + lc) * 136 + wm * 64 + mt * 16 + quad * 4) = o;
                    }
                }
            }
            __syncthreads();
            const int bh2 = bh2base + rd;
#pragma unroll
            for (int p = 0; p < 4; ++p) {
                const int n = p * 16 + (tid >> 4), c = tid & 15;
                b16x8 v = *(const b16x8*)(Sl + n * 136 + c * 8);
                *(b16x8*)(Vtg + (size_t)(bh2 * 64 + n) * 2048 + s0 + c * 8) = v;
            }
        }
        return;
    }

    const float* bp = (mat == 0) ? bq : bk;
#pragma unroll
    for (int nt = 0; nt < 4; ++nt) {
        const int n = bn * 128 + wn * 64 + nt * 16 + lc;
        const int cm = n & 1023;
        const int h = cm >> 6, dh = cm & 63;
        const float bval = bp[cm];
#pragma unroll
        for (int mt = 0; mt < 4; ++mt) {
            const int m0 = bm * 128 + wm * 64 + mt * 16 + quad * 4;
            const int b = m0 >> 11;
            const int bh = b * 16 + h;
            const int s0 = m0 & 2047;
            if (mat == 0) {
#pragma unroll
                for (int r = 0; r < 4; ++r)
                    Qg[(size_t)(bh * 2048 + s0 + r) * 64 + dh] =
                        (b16)((acc[mt][nt][r] + bval) * QSCALE);
            } else {
#pragma unroll
                for (int r = 0; r < 4; ++r)
                    Kg[(size_t)(bh * 2048 + s0 + r) * 64 + dh] =
                        (b16)(acc[mt][nt][r] + bval);
            }
        }
    }
}

// ---------- kernel 4: flash attention, 8 waves/block for MFMA<->VALU overlap ----------
// Grid (32 bh, 8 qb) = 256 blocks, 1/CU (r6: FETCH 12.4 MB, L2 reuse works).
// 512 threads = 8 waves = 2 waves/SIMD: one wave's exp2/cvt overlaps the
// other's MFMA (m114). Each wave owns 32 q rows. P stays in registers; l is
// accumulated by MFMA against a ones-vector (no VALU adds, no shuffles).
// Epilogue bounces through Es so AO writes are 128B lane-contiguous.
__global__ __launch_bounds__(512) void k_flash(
    const b16* __restrict__ Qg, const b16* __restrict__ Kg,
    const b16* __restrict__ Vtg, b16* __restrict__ AO) {
    __shared__ __align__(16) b16 Ks[2][64 * 64];
    __shared__ __align__(16) b16 Vs[2][64 * 64];
    __shared__ __align__(16) b16 Es[256 * 72];   // epilogue bounce (36 KB)
    const int bh = blockIdx.x;        // 0..31 (x-fastest => bh%8 picks XCD)
    const int qb = blockIdx.y;        // 0..7 : 256-row q block
    const int tid = threadIdx.x, lane = tid & 63, wave = tid >> 6;  // wave 0..7
    const int quad = lane >> 4, lc = lane & 15;

    // Q fragments (B-operand of 16x16x32), 32 q rows per wave
    const b16* Qbase = Qg + ((size_t)bh * 2048 + qb * 256 + wave * 32) * 64;
    b16x8 qf[2][2];
#pragma unroll
    for (int qt = 0; qt < 2; ++qt)
#pragma unroll
        for (int ch = 0; ch < 2; ++ch)
            qf[qt][ch] = *(const b16x8*)(Qbase + (qt * 16 + lc) * 64 + ch * 32 + quad * 8);

    // oacc[dt][qt] holds O^T: d = dt*16 + quad*4 + r, q = qt*16 + lc
    f32x4 oacc[4][2] = {};
    f32x4 lacc[2] = {};                     // all 4 regs end up = lsum(q)
    const s16x4 ones = { (short)0x3F80, (short)0x3F80,
                         (short)0x3F80, (short)0x3F80 };  // bf16 1.0 x4

    const b16* Kbh = Kg + (size_t)bh * 2048 * 64;
    const b16* Vbh = Vtg + (size_t)bh * 64 * 2048;

    const int ci = tid;                      // 0..511: exactly one 16B chunk each
    const int rS = ci >> 3, gS = (ci & 7) ^ (rS & 7);   // XOR chunk swizzle

    // prologue: stage tile 0 into buf 0
    async_cp16(&Ks[0][ci * 8], Kbh + (size_t)rS * 64 + gS * 8);
    async_cp16(&Vs[0][ci * 8], Vbh + (size_t)rS * 2048 + gS * 8);
    int cur = 0;

    for (int kt = 0; kt < 32; ++kt) {
        __syncthreads();
        if (kt + 1 < 32) {
            const int nk = kt + 1, nb = cur ^ 1;
            async_cp16(&Ks[nb][ci * 8], Kbh + (size_t)(nk * 64 + rS) * 64 + gS * 8);
            async_cp16(&Vs[nb][ci * 8], Vbh + (size_t)rS * 2048 + nk * 64 + gS * 8);
        }

        const b16* Kc = Ks[cur];
        const b16* Vc = Vs[cur];
#pragma unroll
        for (int m = 0; m < 4; ++m) {          // 16-key block
            const int row = m * 16 + lc;
            const b16x8 kf0 = *(const b16x8*)(Kc + row * 64 + ((quad) ^ (row & 7)) * 8);
            const b16x8 kf1 = *(const b16x8*)(Kc + row * 64 + ((4 + quad) ^ (row & 7)) * 8);

            s16x4 pb[2];
#pragma unroll
            for (int qt = 0; qt < 2; ++qt) {
                f32x4 s = {};
                s = __builtin_amdgcn_mfma_f32_16x16x32_bf16(kf0, qf[qt][0], s, 0, 0, 0);
                s = __builtin_amdgcn_mfma_f32_16x16x32_bf16(kf1, qf[qt][1], s, 0, 0, 0);
                b16x4 p = { (b16)EXP2F(s[0]), (b16)EXP2F(s[1]),
                            (b16)EXP2F(s[2]), (b16)EXP2F(s[3]) };
                pb[qt] = __builtin_bit_cast(s16x4, p);
            }
            // V^T fragments for key-step m: A[m=d][k=quad*4+j] -> b64 reads
            s16x4 vf[4];
#pragma unroll
            for (int dt = 0; dt < 4; ++dt) {
                const int vrow = dt * 16 + lc;
                const int chunk = (m * 2 + (quad >> 1)) ^ (vrow & 7);
                vf[dt] = *(const s16x4*)(Vc + vrow * 64 + chunk * 8 + (quad & 1) * 4);
            }
#pragma unroll
            for (int dt = 0; dt < 4; ++dt)
#pragma unroll
                for (int qt = 0; qt < 2; ++qt)
                    oacc[dt][qt] = __builtin_amdgcn_mfma_f32_16x16x16bf16_1k(
                        vf[dt], pb[qt], oacc[dt][qt], 0, 0, 0);
#pragma unroll
            for (int qt = 0; qt < 2; ++qt)
                lacc[qt] = __builtin_amdgcn_mfma_f32_16x16x16bf16_1k(
                    ones, pb[qt], lacc[qt], 0, 0, 0);
        }
        cur ^= 1;
    }

    // epilogue via LDS bounce: wave-private Es rows -> no barrier before store
    const int b = bh >> 4, h = bh & 15;
#pragma unroll
    for (int qt = 0; qt < 2; ++qt) {
        const float inv = 1.0f / lacc[qt][0];   // every reg/quad holds lsum(q)
        const int qrow = wave * 32 + qt * 16 + lc;
#pragma unroll
        for (int dt = 0; dt < 4; ++dt) {
            b16x4 ob = { (b16)(oacc[dt][qt][0] * inv), (b16)(oacc[dt][qt][1] * inv),
                         (b16)(oacc[dt][qt][2] * inv), (b16)(oacc[dt][qt][3] * inv) };
            *(b16x4*)(Es + qrow * 72 + dt * 16 + quad * 4) = ob;
        }
    }
    __syncthreads();
    const size_t aobase = (size_t)(b * 2048 + qb * 256) * 1024 + h * 64;
#pragma unroll
    for (int p = 0; p < 4; ++p) {
        const int q = p * 64 + (tid >> 3);
        const int c = tid & 7;
        b16x8 v = *(const b16x8*)(Es + q * 72 + c * 8);
        *(b16x8*)(AO + aobase + (size_t)q * 1024 + c * 8) = v;   // 128B/row contiguous
    }
}

// ---------- kernel 5: output projection, 64x128 tiles, dbuf core ----------
// Grid: bn on x so same-B-tile blocks share an XCD (B slice L2-resident).
__global__ __launch_bounds__(256, 2) void k_gemm_out(
    const b16* __restrict__ A, const b16* __restrict__ Bt,
    const float* __restrict__ bo, float* __restrict__ out) {
    __shared__ __align__(16) b16 As[2 * 64 * 32];
    __shared__ __align__(16) b16 Bs[2 * 128 * 32];
    const int bn = blockIdx.x, bm = blockIdx.y;
    const int tid = threadIdx.x;
    const int lane = tid & 63, wave = tid >> 6;
    const int wm = wave & 1, wn = wave >> 1;
    const int quad = lane >> 4, lc = lane & 15;
    const b16* Ab = A + (size_t)(bm * 64) * 1024;
    const b16* Bb = Bt + (size_t)(bn * 128) * 1024;

    const int ci0 = tid, ci1 = tid + 256;
    async_cp16(&As[ci0 * 8], Ab + (size_t)(ci0 >> 2) * 1024 + (ci0 & 3) * 8);
    async_cp16(&Bs[ci0 * 8], Bb + (size_t)(ci0 >> 2) * 1024 + (ci0 & 3) * 8);
    async_cp16(&Bs[ci1 * 8], Bb + (size_t)(ci1 >> 2) * 1024 + (ci1 & 3) * 8);

    f32x4 acc[2][4] = {};
    int cur = 0;
    for (int k0 = 0; k0 < 1024; k0 += 32) {
        __syncthreads();
        if (k0 + 32 < 1024) {
            const int kn = k0 + 32, nb = cur ^ 1;
            async_cp16(&As[nb * 2048 + ci0 * 8], Ab + (size_t)(ci0 >> 2) * 1024 + kn + (ci0 & 3) * 8);
            async_cp16(&Bs[nb * 4096 + ci0 * 8], Bb + (size_t)(ci0 >> 2) * 1024 + kn + (ci0 & 3) * 8);
            async_cp16(&Bs[nb * 4096 + ci1 * 8], Bb + (size_t)(ci1 >> 2) * 1024 + kn + (ci1 & 3) * 8);
        }
        const b16* Ac = &As[cur * 2048];
        const b16* Bc = &Bs[cur * 4096];
        b16x8 af[2], bfr[4];
#pragma unroll
        for (int mt = 0; mt < 2; ++mt)
            af[mt] = *(const b16x8*)(Ac + (wm * 32 + mt * 16 + lc) * 32 + quad * 8);
#pragma unroll
        for (int nt = 0; nt < 4; ++nt)
            bfr[nt] = *(const b16x8*)(Bc + (wn * 64 + nt * 16 + lc) * 32 + quad * 8);
#pragma unroll
        for (int mt = 0; mt < 2; ++mt)
#pragma unroll
            for (int nt = 0; nt < 4; ++nt)
                acc[mt][nt] = __builtin_amdgcn_mfma_f32_16x16x32_bf16(
                    af[mt], bfr[nt], acc[mt][nt], 0, 0, 0);
        cur ^= 1;
    }

#pragma unroll
    for (int nt = 0; nt < 4; ++nt) {
        const int n = bn * 128 + wn * 64 + nt * 16 + lc;
        const float bval = bo[n];
#pragma unroll
        for (int mt = 0; mt < 2; ++mt) {
            const int m0 = bm * 64 + wm * 32 + mt * 16 + quad * 4;
#pragma unroll
            for (int r = 0; r < 4; ++r)
                out[(size_t)(m0 + r) * 1024 + n] = acc[mt][nt][r] + bval;  // 64B/quad contiguous
        }
    }
}

// ---------- launcher ----------
extern "C" void kernel_launch(void* const* d_in, const int* in_sizes, int n_in,
                              void* d_out, int out_size, void* d_ws, size_t ws_size,
                              hipStream_t stream) {
    const float* x  = (const float*)d_in[0];
    const float* Wq = (const float*)d_in[1];
    const float* bq = (const float*)d_in[2];
    const float* Wk = (const float*)d_in[3];
    const float* bk = (const float*)d_in[4];
    const float* Wv = (const float*)d_in[5];
    const float* bv = (const float*)d_in[6];
    const float* Wo = (const float*)d_in[7];
    const float* bo = (const float*)d_in[8];
    float* out = (float*)d_out;

    char* ws = (char*)d_ws;
    const size_t MB = 1024 * 1024;
    b16* Xb  = (b16*)(ws);             // [4096][1024] bf16 (dead after qkv)
    b16* AO  = (b16*)(ws);             // [4096][1024] bf16 (overlay on Xb)
    b16* WtQ = (b16*)(ws + 8 * MB);    // [3072][1024] bf16
    b16* Wot = (b16*)(ws + 14 * MB);   // [1024][1024] bf16
    b16* Qg  = (b16*)(ws + 16 * MB);   // [32][2048][64] bf16 (pre-scaled)
    b16* Kg  = (b16*)(ws + 24 * MB);   // [32][2048][64] bf16
    b16* Vtg = (b16*)(ws + 32 * MB);   // [32][64][2048] bf16

    k_cvt_x<<<4096, 256, 0, stream>>>(x, Xb);
    k_transpose<<<dim3(32, 32, 4), 256, 0, stream>>>(Wq, Wk, Wv, Wo, WtQ, Wot);
    k_gemm_qkv<<<dim3(24, 32), 256, 0, stream>>>(Xb, WtQ, bq, bk, bv, Qg, Kg, Vtg);
    k_flash<<<dim3(32, 8), 512, 0, stream>>>(Qg, Kg, Vtg, AO);
    k_gemm_out<<<dim3(8, 64), 256, 0, stream>>>(AO, Wot, bo, out);
}